// Round 11
// baseline (199.885 us; speedup 1.0000x reference)
//
#include <hip/hip_runtime.h>

// HenonLayer: 4x { t=tanh(Y@W_in+b); grad=((1-t^2)*W_out)@W_in.T; X'=Y+eta; Y'=-X+grad }
// B=2e6, DIM=2, NI=64, fp32. eps=1.
//
// Round-14: revert r13's shared-rcp (neutral: longer serial chain ate the trans
// saving). Base = round-11 (verified 117.4us): 8 rows/thread, 4 v2f slots,
// forced v_pk_fma_f32, deg-3 Taylor (8pk+2rcp/body).
// SINGLE mechanism change vs r11: per-neuron constants via VMEM, not SMEM.
// r11 idle analysis: 26% of cycles idle; constants go s_load + lgkmcnt with no
// SGPR headroom to double-buffer, and the ~4 waves/SIMD run the same code ->
// phase-correlated stalls at every 4-neuron boundary leave the SIMD idle.
// Fix: opaque VGPR zero (asm v_mov) added to the table pointer forces all
// constant addresses VGPR-resident -> global_load_dwordx2 (deep vmcnt queue,
// partial waits, compiler software-pipelines across the unroll-4 blocks).
// Table is 2.5KB -> L1-resident. Asm helpers all-"v" (untied, r11-proven
// style); instruction count per body unchanged.
// cosh^2 ~= 1 + x + x^2/3 + 2x^3/45 (x=a^2); max sech^2 err ~4e-3, 36x under
// the 0.109 threshold (absmax 0.03125 observed at deg-3).

#define NI 64

#define D3 4.444444444e-2f
#define D2 3.333333333e-1f
// higher-order coeffs kept only for the henon_raw fallback (deg-5 poly)
#define D4 3.174603175e-3f
#define D5 1.410934744e-4f

typedef float v2f __attribute__((ext_vector_type(2)));

__device__ __forceinline__ v2f splat(float s) { return (v2f){s, s}; }

// d = a*b + c, all VGPR (untied, distinct dest).
__device__ __forceinline__ v2f pk_fma(v2f a, v2f b, v2f c) {
  v2f d;
  asm("v_pk_fma_f32 %0, %1, %2, %3" : "=v"(d) : "v"(a), "v"(b), "v"(c));
  return d;
}
// d = a*b, all VGPR.
__device__ __forceinline__ v2f pk_mul(v2f a, v2f b) {
  v2f d;
  asm("v_pk_mul_f32 %0, %1, %2" : "=v"(d) : "v"(a), "v"(b));
  return d;
}

// d_ws table (floats): [0:128) w0 pairs | [128:256) w1 pairs | [256:384) b pairs
// | [384:512) c0 pairs | [512:640) c1 pairs | [640],[641] eta
__global__ __launch_bounds__(64) void henon_prep(
    const float* __restrict__ W_in, const float* __restrict__ W_out,
    const float* __restrict__ b_in, const float* __restrict__ eta,
    float* __restrict__ P) {
  int i = threadIdx.x;
  float w0 = W_in[i];
  float w1 = W_in[NI + i];
  float b = b_in[i];
  float wo = W_out[i];
  P[2 * i] = w0;       P[2 * i + 1] = w0;
  P[128 + 2 * i] = w1; P[128 + 2 * i + 1] = w1;
  P[256 + 2 * i] = b;  P[256 + 2 * i + 1] = b;
  float c0 = wo * w0, c1 = wo * w1;
  P[384 + 2 * i] = c0; P[384 + 2 * i + 1] = c0;
  P[512 + 2 * i] = c1; P[512 + 2 * i + 1] = c1;
  if (i < 2) P[640 + i] = eta[i];
}

__global__ __launch_bounds__(256) void henon8(
    const float4* __restrict__ z, const float* __restrict__ P,
    float4* __restrict__ out, int batch) {
  // Opaque zero in a VGPR: defeats uniformity analysis so constant loads take
  // the VMEM path (global_load_dwordx2, deep pipelining) instead of s_load.
  int zv;
  asm("v_mov_b32 %0, 0" : "=v"(zv));

  const v2f* __restrict__ Pw0 = (const v2f*)P + zv;
  const v2f* __restrict__ Pw1 = (const v2f*)(P + 128) + zv;
  const v2f* __restrict__ Pb  = (const v2f*)(P + 256) + zv;
  const v2f* __restrict__ Pc0 = (const v2f*)(P + 384) + zv;
  const v2f* __restrict__ Pc1 = (const v2f*)(P + 512) + zv;
  float e0 = P[640], e1 = P[641];

  // Poly constants resident in VGPR pairs.
  const v2f kD3 = splat(D3);
  const v2f kD2 = splat(D2);
  const v2f kONE = splat(1.0f);

  int tid = blockIdx.x * blockDim.x + threadIdx.x;
  int nthr = gridDim.x * blockDim.x;
  int ngroups = batch >> 3;

  for (int g = tid; g < ngroups; g += nthr) {
    int r = g << 3;
    float4 v[8];
#pragma unroll
    for (int k = 0; k < 8; ++k) v[k] = z[r + k];

    v2f X0[4], X1[4], Y0[4], Y1[4];
#pragma unroll
    for (int p = 0; p < 4; ++p) {
      X0[p] = (v2f){v[2 * p].x, v[2 * p + 1].x};
      X1[p] = (v2f){v[2 * p].y, v[2 * p + 1].y};
      Y0[p] = (v2f){v[2 * p].z, v[2 * p + 1].z};
      Y1[p] = (v2f){v[2 * p].w, v[2 * p + 1].w};
    }

#pragma unroll 1
    for (int it = 0; it < 4; ++it) {
      v2f g0[4], g1[4];
#pragma unroll
      for (int p = 0; p < 4; ++p) { g0[p] = splat(0.f); g1[p] = splat(0.f); }
#pragma unroll 4
      for (int i = 0; i < NI; ++i) {
        v2f w0 = Pw0[i], w1 = Pw1[i], bv = Pb[i];   // global_load_dwordx2 (L1)
        v2f c0 = Pc0[i], c1 = Pc1[i];
#pragma unroll
        for (int p = 0; p < 4; ++p) {
          v2f t = pk_fma(Y1[p], w1, bv);
          v2f a = pk_fma(Y0[p], w0, t);
          v2f x = pk_mul(a, a);
          v2f q = pk_fma(x, kD3, kD2);   // deg-3 Horner start
          q = pk_fma(q, x, kONE);
          q = pk_fma(q, x, kONE);
          v2f s;
          s.x = __builtin_amdgcn_rcpf(q.x);
          s.y = __builtin_amdgcn_rcpf(q.y);
          g0[p] = pk_fma(s, c0, g0[p]);
          g1[p] = pk_fma(s, c1, g1[p]);
        }
      }
#pragma unroll
      for (int p = 0; p < 4; ++p) {
        v2f nX0 = Y0[p] + splat(e0);
        v2f nX1 = Y1[p] + splat(e1);
        Y0[p] = g0[p] - X0[p];
        Y1[p] = g1[p] - X1[p];
        X0[p] = nX0;
        X1[p] = nX1;
      }
    }
#pragma unroll
    for (int p = 0; p < 4; ++p) {
      out[r + 2 * p]     = make_float4(X0[p].x, X1[p].x, Y0[p].x, Y1[p].x);
      out[r + 2 * p + 1] = make_float4(X0[p].y, X1[p].y, Y0[p].y, Y1[p].y);
    }
  }

  // Tail rows (batch % 8), scalar path (deg-3, matches main loop).
  int tail = batch & 7;
  if (tail && tid < tail) {
    int row = (ngroups << 3) + tid;
    float4 v = z[row];
    float X0 = v.x, X1 = v.y, Y0 = v.z, Y1 = v.w;
    for (int it = 0; it < 4; ++it) {
      float g0 = 0.f, g1 = 0.f;
      for (int i = 0; i < NI; ++i) {
        float a = fmaf(Y0, Pw0[i].x, fmaf(Y1, Pw1[i].x, Pb[i].x));
        float x = a * a;
        float q = fmaf(x, D3, D2);
        q = fmaf(q, x, 1.0f);
        q = fmaf(q, x, 1.0f);
        float s = __builtin_amdgcn_rcpf(q);
        g0 = fmaf(s, Pc0[i].x, g0);
        g1 = fmaf(s, Pc1[i].x, g1);
      }
      float nX0 = Y0 + e0, nX1 = Y1 + e1;
      Y0 = g0 - X0;
      Y1 = g1 - X1;
      X0 = nX0;
      X1 = nX1;
    }
    out[row] = make_float4(X0, X1, Y0, Y1);
  }
}

// Fallback if ws too small for the table: raw weights, 1 row/thread (deg-5 poly).
__global__ __launch_bounds__(256) void henon_raw(
    const float4* __restrict__ z, const float* __restrict__ W_in,
    const float* __restrict__ W_out, const float* __restrict__ b_in,
    const float* __restrict__ eta, float4* __restrict__ out, int batch) {
  int idx = blockIdx.x * blockDim.x + threadIdx.x;
  int stride = gridDim.x * blockDim.x;
  float e0 = eta[0], e1 = eta[1];
  for (int row = idx; row < batch; row += stride) {
    float4 v = z[row];
    float X0 = v.x, X1 = v.y, Y0 = v.z, Y1 = v.w;
    for (int it = 0; it < 4; ++it) {
      float g0 = 0.f, g1 = 0.f;
#pragma unroll
      for (int i = 0; i < NI; ++i) {
        float w0 = W_in[i], w1 = W_in[NI + i];
        float a = fmaf(Y0, w0, fmaf(Y1, w1, b_in[i]));
        float x = a * a;
        float q = fmaf(x, D5, D4);
        q = fmaf(q, x, D3);
        q = fmaf(q, x, D2);
        q = fmaf(q, x, 1.0f);
        q = fmaf(q, x, 1.0f);
        float s = __builtin_amdgcn_rcpf(q) * W_out[i];
        g0 = fmaf(s, w0, g0);
        g1 = fmaf(s, w1, g1);
      }
      float nX0 = Y0 + e0, nX1 = Y1 + e1;
      Y0 = g0 - X0;
      Y1 = g1 - X1;
      X0 = nX0;
      X1 = nX1;
    }
    out[row] = make_float4(X0, X1, Y0, Y1);
  }
}

extern "C" void kernel_launch(void* const* d_in, const int* in_sizes, int n_in,
                              void* d_out, int out_size, void* d_ws, size_t ws_size,
                              hipStream_t stream) {
  const float4* z = (const float4*)d_in[0];
  const float* W_in = (const float*)d_in[1];
  const float* W_out = (const float*)d_in[2];
  const float* b_in = (const float*)d_in[3];
  const float* eta = (const float*)d_in[4];
  float4* out = (float4*)d_out;

  int batch = in_sizes[0] / 4;  // 2,000,000 rows

  if (ws_size >= 642 * sizeof(float)) {
    float* P = (float*)d_ws;
    henon_prep<<<1, 64, 0, stream>>>(W_in, W_out, b_in, eta, P);
    int ngroups = (batch + 7) >> 3;
    int blocks = (ngroups + 255) / 256;
    henon8<<<blocks, 256, 0, stream>>>(z, P, out, batch);
  } else {
    int blocks = (batch + 255) / 256;
    henon_raw<<<blocks, 256, 0, stream>>>(z, W_in, W_out, b_in, eta, out, batch);
  }
}

// Round 14
// 179.174 us; speedup vs baseline: 1.1156x; 1.1156x over previous
//
#include <hip/hip_runtime.h>

// HenonLayer: 4x { t=tanh(Y@W_in+b); grad=((1-t^2)*W_out)@W_in.T; X'=Y+eta; Y'=-X+grad }
// B=2e6, DIM=2, NI=64, fp32. eps=1.
//
// Round-17: r16's op_sel SGPR-broadcast REJECTED by the gfx950 assembler
// (VOP3P op_sel requires VGPR sources); path abandoned, no perf data.
// Base = round-11 (verified 117.4us x4 runs): 8 rows/thread, 4 v2f slots,
// forced v_pk_fma_f32 via asm, "s"-pair constants, deg-3 Taylor (8pk+2rcp).
// SINGLE change vs r11: neuron-loop unroll 4 -> 8 (pragma-only; the one edit
// class that has never miscompiled this kernel). Halves the phase-correlated
// s_load/lgkmcnt stall boundaries (16 -> 8 per it-loop) that the idle-cycle
// analysis fingered (~35% latency-idle vs issue model); compiler batches 40
// dwords of s_load per block under more covering compute. SGPR window 40->80
// of ~102 budget -- fits.
// cosh^2 ~= 1 + x + x^2/3 + 2x^3/45 (x=a^2); max sech^2 err ~4e-3, 36x under
// the 0.109 threshold (absmax 0.03125 verified at deg-3).

#define NI 64

#define D3 4.444444444e-2f
#define D2 3.333333333e-1f
// higher-order coeffs kept only for the henon_raw fallback (deg-5 poly)
#define D4 3.174603175e-3f
#define D5 1.410934744e-4f

typedef float v2f __attribute__((ext_vector_type(2)));

__device__ __forceinline__ v2f splat(float s) { return (v2f){s, s}; }

// d = a*b + c, b from SGPR pair (uniform), a/c VGPR pairs.
__device__ __forceinline__ v2f pk_fma_vsv(v2f a, v2f b, v2f c) {
  v2f d;
  asm("v_pk_fma_f32 %0, %1, %2, %3" : "=v"(d) : "v"(a), "s"(b), "v"(c));
  return d;
}
// d = a*b + c, c from SGPR pair (uniform constant), a/b VGPR pairs.
__device__ __forceinline__ v2f pk_fma_vvs(v2f a, v2f b, v2f c) {
  v2f d;
  asm("v_pk_fma_f32 %0, %1, %2, %3" : "=v"(d) : "v"(a), "v"(b), "s"(c));
  return d;
}
// d = a*b, all VGPR.
__device__ __forceinline__ v2f pk_mul_vv(v2f a, v2f b) {
  v2f d;
  asm("v_pk_mul_f32 %0, %1, %2" : "=v"(d) : "v"(a), "v"(b));
  return d;
}

// d_ws table (floats): [0:128) w0 pairs | [128:256) w1 pairs | [256:384) b pairs
// | [384:512) c0 pairs | [512:640) c1 pairs | [640],[641] eta
__global__ __launch_bounds__(64) void henon_prep(
    const float* __restrict__ W_in, const float* __restrict__ W_out,
    const float* __restrict__ b_in, const float* __restrict__ eta,
    float* __restrict__ P) {
  int i = threadIdx.x;
  float w0 = W_in[i];
  float w1 = W_in[NI + i];
  float b = b_in[i];
  float wo = W_out[i];
  P[2 * i] = w0;       P[2 * i + 1] = w0;
  P[128 + 2 * i] = w1; P[128 + 2 * i + 1] = w1;
  P[256 + 2 * i] = b;  P[256 + 2 * i + 1] = b;
  float c0 = wo * w0, c1 = wo * w1;
  P[384 + 2 * i] = c0; P[384 + 2 * i + 1] = c0;
  P[512 + 2 * i] = c1; P[512 + 2 * i + 1] = c1;
  if (i < 2) P[640 + i] = eta[i];
}

__global__ __launch_bounds__(256) void henon8(
    const float4* __restrict__ z, const float* __restrict__ P,
    float4* __restrict__ out, int batch) {
  const v2f* __restrict__ Pw0 = (const v2f*)P;
  const v2f* __restrict__ Pw1 = (const v2f*)(P + 128);
  const v2f* __restrict__ Pb  = (const v2f*)(P + 256);
  const v2f* __restrict__ Pc0 = (const v2f*)(P + 384);
  const v2f* __restrict__ Pc1 = (const v2f*)(P + 512);
  float e0 = P[640], e1 = P[641];

  // Poly constants: kD3 consumed from SGPR ("s"), kD2 resident in a VGPR pair
  // (c-slot of the first poly fma), kONE via "s".
  const v2f kD3 = splat(D3);
  const v2f kD2 = splat(D2);
  const v2f kONE = splat(1.0f);

  int tid = blockIdx.x * blockDim.x + threadIdx.x;
  int nthr = gridDim.x * blockDim.x;
  int ngroups = batch >> 3;

  for (int g = tid; g < ngroups; g += nthr) {
    int r = g << 3;
    float4 v[8];
#pragma unroll
    for (int k = 0; k < 8; ++k) v[k] = z[r + k];

    v2f X0[4], X1[4], Y0[4], Y1[4];
#pragma unroll
    for (int p = 0; p < 4; ++p) {
      X0[p] = (v2f){v[2 * p].x, v[2 * p + 1].x};
      X1[p] = (v2f){v[2 * p].y, v[2 * p + 1].y};
      Y0[p] = (v2f){v[2 * p].z, v[2 * p + 1].z};
      Y1[p] = (v2f){v[2 * p].w, v[2 * p + 1].w};
    }

#pragma unroll 1
    for (int it = 0; it < 4; ++it) {
      v2f g0[4], g1[4];
#pragma unroll
      for (int p = 0; p < 4; ++p) { g0[p] = splat(0.f); g1[p] = splat(0.f); }
#pragma unroll 8
      for (int i = 0; i < NI; ++i) {
        v2f w0 = Pw0[i], w1 = Pw1[i];  // stay in SGPR pairs ("s" operands)
        v2f c0 = Pc0[i], c1 = Pc1[i];  // stay in SGPR pairs ("s" operands)
        v2f bv = Pb[i];                // copied to VGPR pair (c-slot of first fma)
#pragma unroll
        for (int p = 0; p < 4; ++p) {
          v2f t = pk_fma_vsv(Y1[p], w1, bv);
          v2f a = pk_fma_vsv(Y0[p], w0, t);
          v2f x = pk_mul_vv(a, a);
          v2f q = pk_fma_vsv(x, kD3, kD2);   // deg-3 Horner start
          q = pk_fma_vvs(q, x, kONE);
          q = pk_fma_vvs(q, x, kONE);
          v2f s;
          s.x = __builtin_amdgcn_rcpf(q.x);
          s.y = __builtin_amdgcn_rcpf(q.y);
          g0[p] = pk_fma_vsv(s, c0, g0[p]);
          g1[p] = pk_fma_vsv(s, c1, g1[p]);
        }
      }
#pragma unroll
      for (int p = 0; p < 4; ++p) {
        v2f nX0 = Y0[p] + splat(e0);
        v2f nX1 = Y1[p] + splat(e1);
        Y0[p] = g0[p] - X0[p];
        Y1[p] = g1[p] - X1[p];
        X0[p] = nX0;
        X1[p] = nX1;
      }
    }
#pragma unroll
    for (int p = 0; p < 4; ++p) {
      out[r + 2 * p]     = make_float4(X0[p].x, X1[p].x, Y0[p].x, Y1[p].x);
      out[r + 2 * p + 1] = make_float4(X0[p].y, X1[p].y, Y0[p].y, Y1[p].y);
    }
  }

  // Tail rows (batch % 8), scalar path (deg-3, matches main loop).
  int tail = batch & 7;
  if (tail && tid < tail) {
    int row = (ngroups << 3) + tid;
    float4 v = z[row];
    float X0 = v.x, X1 = v.y, Y0 = v.z, Y1 = v.w;
    for (int it = 0; it < 4; ++it) {
      float g0 = 0.f, g1 = 0.f;
      for (int i = 0; i < NI; ++i) {
        float a = fmaf(Y0, Pw0[i].x, fmaf(Y1, Pw1[i].x, Pb[i].x));
        float x = a * a;
        float q = fmaf(x, D3, D2);
        q = fmaf(q, x, 1.0f);
        q = fmaf(q, x, 1.0f);
        float s = __builtin_amdgcn_rcpf(q);
        g0 = fmaf(s, Pc0[i].x, g0);
        g1 = fmaf(s, Pc1[i].x, g1);
      }
      float nX0 = Y0 + e0, nX1 = Y1 + e1;
      Y0 = g0 - X0;
      Y1 = g1 - X1;
      X0 = nX0;
      X1 = nX1;
    }
    out[row] = make_float4(X0, X1, Y0, Y1);
  }
}

// Fallback if ws too small for the table: raw weights, 1 row/thread (deg-5 poly).
__global__ __launch_bounds__(256) void henon_raw(
    const float4* __restrict__ z, const float* __restrict__ W_in,
    const float* __restrict__ W_out, const float* __restrict__ b_in,
    const float* __restrict__ eta, float4* __restrict__ out, int batch) {
  int idx = blockIdx.x * blockDim.x + threadIdx.x;
  int stride = gridDim.x * blockDim.x;
  float e0 = eta[0], e1 = eta[1];
  for (int row = idx; row < batch; row += stride) {
    float4 v = z[row];
    float X0 = v.x, X1 = v.y, Y0 = v.z, Y1 = v.w;
    for (int it = 0; it < 4; ++it) {
      float g0 = 0.f, g1 = 0.f;
#pragma unroll
      for (int i = 0; i < NI; ++i) {
        float w0 = W_in[i], w1 = W_in[NI + i];
        float a = fmaf(Y0, w0, fmaf(Y1, w1, b_in[i]));
        float x = a * a;
        float q = fmaf(x, D5, D4);
        q = fmaf(q, x, D3);
        q = fmaf(q, x, D2);
        q = fmaf(q, x, 1.0f);
        q = fmaf(q, x, 1.0f);
        float s = __builtin_amdgcn_rcpf(q) * W_out[i];
        g0 = fmaf(s, w0, g0);
        g1 = fmaf(s, w1, g1);
      }
      float nX0 = Y0 + e0, nX1 = Y1 + e1;
      Y0 = g0 - X0;
      Y1 = g1 - X1;
      X0 = nX0;
      X1 = nX1;
    }
    out[row] = make_float4(X0, X1, Y0, Y1);
  }
}

extern "C" void kernel_launch(void* const* d_in, const int* in_sizes, int n_in,
                              void* d_out, int out_size, void* d_ws, size_t ws_size,
                              hipStream_t stream) {
  const float4* z = (const float4*)d_in[0];
  const float* W_in = (const float*)d_in[1];
  const float* W_out = (const float*)d_in[2];
  const float* b_in = (const float*)d_in[3];
  const float* eta = (const float*)d_in[4];
  float4* out = (float4*)d_out;

  int batch = in_sizes[0] / 4;  // 2,000,000 rows

  if (ws_size >= 642 * sizeof(float)) {
    float* P = (float*)d_ws;
    henon_prep<<<1, 64, 0, stream>>>(W_in, W_out, b_in, eta, P);
    int ngroups = (batch + 7) >> 3;
    int blocks = (ngroups + 255) / 256;
    henon8<<<blocks, 256, 0, stream>>>(z, P, out, batch);
  } else {
    int blocks = (batch + 255) / 256;
    henon_raw<<<blocks, 256, 0, stream>>>(z, W_in, W_out, b_in, eta, out, batch);
  }
}